// Round 8
// baseline (29.492 us; speedup 1.0000x reference)
//
#include <hip/hip_runtime.h>

// Problem constants
#define NSTEPS 255
#define TPTS   256          // time points incl t=0
#define NTRAJ  16384        // total trajectories
#define NBLK   256          // integration blocks, 64 trajectories each
#define ROWB   2040         // bytes per wvec row = 255 steps * 8 B (8-mod-16!)

#define GAMMA_F 0.36f
#define OMEGA_F 5.0265f
#define DT_F    0.00390625f          // 2^-8
#define CW      0.0375f              // sqrt(GAMMA)*sqrt(DT) = 0.6/16 (exact)
#define GD      (GAMMA_F * DT_F)
#define OD      (OMEGA_F * DT_F)

// LDS state history: [slot 0..254][lane 0..63] fp16x4 {x,y,z,pad}, pitch 520 B.
// (R7-validated: write + tail read both at structural b64 floor.)
#define PITCH  520
#define STATEB 132608        // 255*520 = 132600, padded to 16B multiple

// LDS w-tile: 64 rows x 128 B (16 steps), padded stride 144 B. Two explicit
// buffers (NO xor toggle — R6's bug was rl^=9216 with 9216 not pow2-aligned).
#define WROW  144
#define WTILE (64 * WROW)   // 9216 B

typedef __fp16 half2v __attribute__((ext_vector_type(2)));
typedef float  f32x2  __attribute__((ext_vector_type(2)));

// pack two f32 -> fp16x2 in one instruction (v_cvt_pkrtz_f16_f32)
__device__ __forceinline__ unsigned pk2(float a, float b) {
  half2v h = __builtin_amdgcn_cvt_pkrtz(a, b);
  return __builtin_bit_cast(unsigned, h);
}

// One Euler-Maruyama step, packed-f32 form (R4/R7-validated math).
// State: v = (x,y), z scalar. Writes fp16x4 state to LDS at sb + ii_*PITCH.
#define STEP2(wx_, wy_, ii_) {                                                  \
  const float w0  = (wx_) * CW;                                                 \
  const f32x2 w1n = nCW2 * (wy_);              /* (-CW*wy, +CW*wy) */           \
  const f32x2 sw  = __builtin_shufflevector(v, v, 1, 0);   /* (y,x) */          \
  f32x2 t = __builtin_elementwise_fma(epack, sw, v);                            \
  t = __builtin_elementwise_fma(mGD2, v, t);                                    \
  const f32x2 p   = v * z;                                                      \
  const f32x2 mw0 = {-w0, -w0};                                                 \
  t = __builtin_elementwise_fma(p, mw0, t);                                     \
  t = __builtin_elementwise_fma(sw, w1n, t);                                    \
  t[1] = __builtin_fmaf(-OD, z, t[1]);                                          \
  const float a_ = __builtin_fmaf(OD, v[1], z);                                 \
  const float r_ = __builtin_fmaf(-(z * z), w0, w0);                            \
  v = t; z = a_ + r_;                                                           \
  *(uint2*)(sb + (ii_) * PITCH) = make_uint2(pk2(v[0], v[1]), pk2(z, 0.0f));    \
}

// Coalesced tile load, 8B granularity (always 8-aligned: r*2040, (l&15)*8,
// co=128c all 0 mod 8). Instr i covers rows 4i+(l>>4) -> 4 contiguous 128B
// segments per instruction (vs 64 scattered segments for the direct scheme).
#define GLOAD(co) {                                                             \
  _Pragma("unroll")                                                             \
  for (int i_ = 0; i_ < 16; ++i_)                                               \
    r2[i_] = *(const float2*)(wbp + (size_t)i_ * (4 * ROWB) + (co));            \
}
// Last chunk (bytes 1920..2039 = 120 B): lane col 15 would read past row end.
#define GLOADP(co) {                                                            \
  if ((l & 15) != 15) {                                                         \
    _Pragma("unroll")                                                           \
    for (int i_ = 0; i_ < 16; ++i_)                                             \
      r2[i_] = *(const float2*)(wbp + (size_t)i_ * (4 * ROWB) + (co));          \
  }                                                                             \
}

// 16x ds_write_b64 into tile WB: row 4i+(l>>4), bytes (l&15)*8 .. +8
#define LDSW(WB) {                                                              \
  _Pragma("unroll")                                                             \
  for (int i_ = 0; i_ < 16; ++i_)                                               \
    *(float2*)((WB) + wl + i_ * (4 * WROW)) = r2[i_];                           \
}

// Consume NK steps from tile WB (lane l reads its own row l; byte 8k = local
// step k; float4 = 2 steps). Advances sb by NK slots.
#define CHUNKN(WB, NK) {                                                        \
  _Pragma("unroll")                                                             \
  for (int p_ = 0; p_ < 8; ++p_) {                                              \
    const float4 wv = *(const float4*)((WB) + rl + p_ * 16);                    \
    STEP2(wv.x, wv.y, 2 * p_);                                                  \
    if (2 * p_ + 1 < (NK)) STEP2(wv.z, wv.w, 2 * p_ + 1);                       \
  }                                                                             \
  sb += (NK) * PITCH;                                                           \
}

// grid = 256 blocks x 64 threads (1 wave); block g owns trajectories g*64..+63.
// Chunk c (c=0..15) = steps 16c..16c+15 at row bytes [128c, 128c+128);
// chunk 15 short: 15 steps (120 B). Single wave -> no barriers in the loop;
// compiler-inserted lgkmcnt orders LDS write->read within the wave.
__global__ __launch_bounds__(64) void sde_integrate(const float* __restrict__ inp,
                                                    const float* __restrict__ wvec,
                                                    float* __restrict__ partial) {
  __shared__ alignas(16) char smem[STATEB + 2 * WTILE];   // 151,040 B
  const int g = blockIdx.x, l = threadIdx.x;
  // trajectory n = g*64+l; eps = inputs[n % 32] = inputs[l & 31]
  const float eps = inp[l & 31];
  const f32x2 epack = {-eps * DT_F, eps * DT_F};
  const f32x2 mGD2  = {-GD, -GD};
  const f32x2 nCW2  = {-CW, CW};

  const char* wbp = (const char*)wvec
      + (size_t)(g * 64 + (l >> 4)) * ROWB + (l & 15) * 8;
  char* const wt0 = smem + STATEB;
  char* const wt1 = wt0 + WTILE;
  const unsigned wl = (unsigned)((l >> 4) * WROW + (l & 15) * 8);
  const unsigned rl = (unsigned)(l * WROW);
  char* sb = smem + l * 8;             // state slot 0, this lane's column

  f32x2 v = {0.0f, 0.0f};
  float z = 1.0f;
  float2 r2[16];                       // static indexing only (regs)

  GLOAD(0);                            // chunk 0
  LDSW(wt0);
  GLOAD(128);                          // chunk 1 prefetch
  CHUNKN(wt0, 16);                     // steps 0..15

  #pragma unroll 1
  for (int c = 1; c <= 14; ++c) {
    char* const wb = (c & 1) ? wt1 : wt0;
    LDSW(wb);                          // r2 holds chunk c
    if (c < 14) { GLOAD(128 * (c + 1)); }
    else        { GLOADP(1920); }      // chunk 15, predicated (120 B)
    CHUNKN(wb, 16);                    // steps 16c..16c+15
  }
  LDSW(wt1);                           // chunk 15 (15&1 = 1)
  CHUNKN(wt1, 15);                     // steps 240..254

  __syncthreads();                     // once, before tail (single wave: cheap)

  // Tail (R7-validated): lane l reduces slots l, l+64, l+128, l+192 (<255).
  #pragma unroll
  for (int k = 0; k < 4; ++k) {
    const int s = l + 64 * k;
    if (s < NSTEPS) {
      const char* rb = smem + (size_t)s * PITCH;
      float fx = 0.0f, fy = 0.0f, fz = 0.0f;
      #pragma unroll
      for (int j = 0; j < 64; ++j) {
        const uint2 u = *(const uint2*)(rb + j * 8);
        const half2v xy = __builtin_bit_cast(half2v, u.x);
        const half2v zp = __builtin_bit_cast(half2v, u.y);
        fx += (float)xy[0];
        fy += (float)xy[1];
        fz += (float)zp[0];
      }
      float* p = partial + ((size_t)g * NSTEPS + s) * 3;
      p[0] = fx; p[1] = fy; p[2] = fz;
    }
  }
}

// one thread per (b, t): sum 8 block-partials, emit 6 probabilities
__global__ __launch_bounds__(256) void sde_finalize(const float* __restrict__ partial,
                                                    float* __restrict__ out) {
  const int idx = blockIdx.x * blockDim.x + threadIdx.x;   // b*256 + t, 8192 total
  const int b = idx >> 8;
  const int t = idx & 255;
  float* o = out + (size_t)idx * 6;

  if (t == 0) {
    // exact initial state (0,0,1): probs = {0.5, 0.5, 0.5, 0.5, 1, 0}
    o[0] = 0.5f; o[1] = 0.5f; o[2] = 0.5f; o[3] = 0.5f;
    o[4] = 1.0f; o[5] = 0.0f;
    return;
  }

  float sx = 0.0f, sy = 0.0f, sz = 0.0f;
  #pragma unroll
  for (int j = 0; j < 8; ++j) {
    const float* p = partial + ((size_t)(b * 8 + j) * NSTEPS + (t - 1)) * 3;
    sx += p[0]; sy += p[1]; sz += p[2];
  }
  const float inv = 1.0f / 512.0f;
  const float mx = sx * inv, my = sy * inv, mz = sz * inv;
  o[0] = 0.5f * (1.0f + mx);
  o[1] = 0.5f * (1.0f - mx);
  o[2] = 0.5f * (1.0f + my);
  o[3] = 0.5f * (1.0f - my);
  o[4] = 0.5f * (1.0f + mz);
  o[5] = 0.5f * (1.0f - mz);
}

extern "C" void kernel_launch(void* const* d_in, const int* in_sizes, int n_in,
                              void* d_out, int out_size, void* d_ws, size_t ws_size,
                              hipStream_t stream) {
  (void)in_sizes; (void)n_in; (void)out_size; (void)ws_size;
  const float* inp  = (const float*)d_in[0];   // [32]
  const float* wvec = (const float*)d_in[1];   // [16384][255][2]
  float* out     = (float*)d_out;              // [32][256][6]
  float* partial = (float*)d_ws;               // 256*255*3*4 = 783360 B

  sde_integrate<<<NBLK, 64, 0, stream>>>(inp, wvec, partial);
  sde_finalize<<<32, 256, 0, stream>>>(partial, out);
}

// Round 9
// 22.992 us; speedup vs baseline: 1.2827x; 1.2827x over previous
//
#include <hip/hip_runtime.h>

// Problem constants
#define NSTEPS 255
#define TPTS   256          // time points incl t=0
#define NTRAJ  16384        // total trajectories
#define NBLK   256          // integration blocks, 64 trajectories each
#define CH     15           // steps per prefetch chunk; 17*15 = 255

#define GAMMA_F 0.36f
#define OMEGA_F 5.0265f
#define DT_F    0.00390625f          // 2^-8
#define CW      0.0375f              // sqrt(GAMMA)*sqrt(DT) = 0.6/16 (exact)
#define GD      (GAMMA_F * DT_F)
#define OD      (OMEGA_F * DT_F)

// LDS state history: [slot 0..254][lane 0..63] fp16x4 {x,y,z,pad}, pitch 520 B.
// (R7-validated: per-step b64 writes lanes-consecutive; tail reads lane-stride
// 520 B -> start bank 2l mod 32 -> only 2-way aliasing = free.)
#define PITCH  520
#define STATEB 132608        // 255*520 = 132600, padded

typedef __fp16 half2v __attribute__((ext_vector_type(2)));
typedef float  f32x2  __attribute__((ext_vector_type(2)));

// pack two f32 -> fp16x2 in one instruction (v_cvt_pkrtz_f16_f32)
__device__ __forceinline__ unsigned pk2(float a, float b) {
  half2v h = __builtin_amdgcn_cvt_pkrtz(a, b);
  return __builtin_bit_cast(unsigned, h);
}

// One Euler-Maruyama step, packed-f32 form. Bit-identical to the R4/R7
// validated math; operand expressions rewritten so LLVM folds the sign flips
// into VOP3P neg bits and the scalar broadcasts into op_sel_hi (no
// materialized operand vectors):
//   nx = x - eps*dt*y - GD*x - (x*z)*w0 - y*cy
//   ny = y + eps*dt*x - GD*y - (y*z)*w0 + x*cy - OD*z
//   nz = z + OD*y + (1-z*z)*w0
#define STEP2(wx_, wy_, ii_) {                                                  \
  const float w0  = (wx_) * CW;                                                 \
  const float cy  = (wy_) * CW;                                                 \
  const f32x2 sw  = __builtin_shufflevector(v, v, 1, 0);   /* (y,x) */          \
  f32x2 t = __builtin_elementwise_fma(epack, sw, v);                            \
  t = __builtin_elementwise_fma(mGD2, v, t);                                    \
  const f32x2 w0s = {w0, w0};                   /* splat: op_sel_hi */          \
  t = __builtin_elementwise_fma(-(v * z), w0s, t);   /* neg folds */            \
  const f32x2 cys = {-cy, cy};                  /* neg_lo fold */               \
  t = __builtin_elementwise_fma(sw, cys, t);                                    \
  t[1] = __builtin_fmaf(-OD, z, t[1]);                                          \
  const float a_ = __builtin_fmaf(OD, v[1], z);                                 \
  const float r_ = __builtin_fmaf(-(z * z), w0, w0);                            \
  v = t; z = a_ + r_;                                                           \
  *(uint2*)(sb + (ii_) * PITCH) = make_uint2(pk2(v[0], v[1]), pk2(z, 0.0f));    \
}

#define LOADC(BUF, CHUNK_) {                                                    \
  _Pragma("unroll")                                                             \
  for (int i_ = 0; i_ < CH; ++i_) BUF[i_] = wrow[(CHUNK_) * CH + i_];           \
}

#define PROC(BUF) {                                                             \
  _Pragma("unroll")                                                             \
  for (int i_ = 0; i_ < CH; ++i_) STEP2((BUF)[i_].x, (BUF)[i_].y, i_)           \
  sb += CH * PITCH;                                                             \
}

// grid = 256 blocks x 64 threads (1 wave); block g owns trajectories g*64..+63.
// R7-validated: direct w loads (distance-2 reg prefetch), per-step LDS state
// write, in-wave tail reduction -> partial[g][slot][3] (f32).
__global__ __launch_bounds__(64) void sde_integrate(const float* __restrict__ inp,
                                                    const float* __restrict__ wvec,
                                                    float* __restrict__ partial) {
  __shared__ alignas(16) char smem[STATEB];
  const int g = blockIdx.x, l = threadIdx.x;
  // trajectory n = g*64+l; eps = inputs[n % 32] = inputs[l & 31]
  const float eps = inp[l & 31];
  const f32x2 epack = {-eps * DT_F, eps * DT_F};
  const f32x2 mGD2  = {-GD, -GD};

  const float2* __restrict__ wrow =
      reinterpret_cast<const float2*>(wvec) + (size_t)(g * 64 + l) * NSTEPS;
  char* sb = smem + l * 8;             // slot 0, this lane's column

  f32x2 v = {0.0f, 0.0f};
  float z = 1.0f;

  float2 bufA[CH], bufB[CH], bufC[CH]; // static indexing only (regs)

  // prefetch distance 2: chunks c and c+1 in flight before computing c
  LOADC(bufA, 0);
  LOADC(bufB, 1);
  #pragma unroll 1
  for (int k = 0; k < 5; ++k) {        // chunks 3k..3k+2, loads 3k+2..3k+4
    LOADC(bufC, 3 * k + 2); PROC(bufA);
    LOADC(bufA, 3 * k + 3); PROC(bufB);
    LOADC(bufB, 3 * k + 4); PROC(bufC);
  }
  PROC(bufA);                          // chunk 15
  PROC(bufB);                          // chunk 16 (slots 240..254)

  __syncthreads();                     // single wave: cheap; orders LDS for tail

  // Tail: lane l reduces slots l, l+64, l+128, l+192 (skip >= 255).
  // (x,y) accumulated as f32x2 (v_pk_add_f32): same per-component order as
  // scalar chains -> bit-identical.
  #pragma unroll
  for (int k = 0; k < 4; ++k) {
    const int s = l + 64 * k;
    if (s < NSTEPS) {
      const char* rb = smem + (size_t)s * PITCH;
      f32x2 sxy = {0.0f, 0.0f};
      float fz = 0.0f;
      #pragma unroll
      for (int j = 0; j < 64; ++j) {
        const uint2 u = *(const uint2*)(rb + j * 8);
        const half2v xy = __builtin_bit_cast(half2v, u.x);
        const half2v zp = __builtin_bit_cast(half2v, u.y);
        const f32x2 vxy = {(float)xy[0], (float)xy[1]};
        sxy += vxy;
        fz += (float)zp[0];
      }
      float* p = partial + ((size_t)g * NSTEPS + s) * 3;
      p[0] = sxy[0]; p[1] = sxy[1]; p[2] = fz;
    }
  }
}

// one thread per (b, t): sum 8 block-partials, emit 6 probabilities.
// 128 blocks x 64 threads = 8192 threads (one per output row).
__global__ __launch_bounds__(64) void sde_finalize(const float* __restrict__ partial,
                                                   float* __restrict__ out) {
  const int idx = blockIdx.x * 64 + threadIdx.x;   // b*256 + t, 8192 total
  const int b = idx >> 8;
  const int t = idx & 255;
  float* o = out + (size_t)idx * 6;

  if (t == 0) {
    // exact initial state (0,0,1): probs = {0.5, 0.5, 0.5, 0.5, 1, 0}
    o[0] = 0.5f; o[1] = 0.5f; o[2] = 0.5f; o[3] = 0.5f;
    o[4] = 1.0f; o[5] = 0.0f;
    return;
  }

  float sx = 0.0f, sy = 0.0f, sz = 0.0f;
  #pragma unroll
  for (int j = 0; j < 8; ++j) {
    const float* p = partial + ((size_t)(b * 8 + j) * NSTEPS + (t - 1)) * 3;
    sx += p[0]; sy += p[1]; sz += p[2];
  }
  const float inv = 1.0f / 512.0f;
  const float mx = sx * inv, my = sy * inv, mz = sz * inv;
  o[0] = 0.5f * (1.0f + mx);
  o[1] = 0.5f * (1.0f - mx);
  o[2] = 0.5f * (1.0f + my);
  o[3] = 0.5f * (1.0f - my);
  o[4] = 0.5f * (1.0f + mz);
  o[5] = 0.5f * (1.0f - mz);
}

extern "C" void kernel_launch(void* const* d_in, const int* in_sizes, int n_in,
                              void* d_out, int out_size, void* d_ws, size_t ws_size,
                              hipStream_t stream) {
  (void)in_sizes; (void)n_in; (void)out_size; (void)ws_size;
  const float* inp  = (const float*)d_in[0];   // [32]
  const float* wvec = (const float*)d_in[1];   // [16384][255][2]
  float* out     = (float*)d_out;              // [32][256][6]
  float* partial = (float*)d_ws;               // 256*255*3*4 = 783360 B

  sde_integrate<<<NBLK, 64, 0, stream>>>(inp, wvec, partial);
  sde_finalize<<<128, 64, 0, stream>>>(partial, out);
}